// Round 10
// baseline (46.697 us; speedup 1.0000x reference)
//
#include <hip/hip_runtime.h>
#include <hip/hip_bf16.h>

// out[n,f] = weights[n] * ( x[n,:] . Wsum[f,:] + bsum[f] )
// Wsum = sum_e W[e], bsum = sum_e b[e]  (expert sum commutes with Linear).
// Wsum stored fragment-major ("Bfrag") -> GEMM B-loads are lane-consecutive dense
// streams (R6-proven, -12.5us). R9: cross-tile pipeline -- 2 tiles per block,
// tile t+1's A-loads issued BEFORE tile t's K-loop (pinned by sched_barrier(0)
// against the load-sinking observed in R5/R7), epilogue stores drain under the
// next K-loop. BM=64 (R8's 128 regressed write amp). Single 64KB LDS buffer.

#define N_TOK 32768
#define DIM   512
#define NEXP  8
#define BM    64            // tokens per tile
#define TILES 2             // tiles per block

typedef __attribute__((ext_vector_type(8))) short  bf16x8;
typedef __attribute__((ext_vector_type(4))) float  f32x4;

__device__ __forceinline__ unsigned int pk2bf(float a, float b) {
    unsigned ua = __float_as_uint(a), ub = __float_as_uint(b);
    ua = (ua + 0x7FFFu + ((ua >> 16) & 1u)) >> 16;   // RNE to bf16
    ub = (ub + 0x7FFFu + ((ub >> 16) & 1u)) >> 16;
    return ua | (ub << 16);
}

// ---------------- prep: Bfrag (bf16, fragment-major) + bsum (f32) ---- (R6-proven) ----
__global__ __launch_bounds__(256) void moe_prep(const float* __restrict__ W,
                                                const float* __restrict__ b,
                                                unsigned short* __restrict__ Bfrag,
                                                float* __restrict__ bsum) {
    const int g = blockIdx.x * 256 + threadIdx.x;    // 0..32767
    const int f = g >> 6;
    const int q = g & 63;
    const float* src = W + (size_t)f * DIM + q * 8;
    float s0 = 0, s1 = 0, s2 = 0, s3 = 0, s4 = 0, s5 = 0, s6 = 0, s7 = 0;
#pragma unroll
    for (int e = 0; e < NEXP; ++e) {
        float4 u0 = *(const float4*)(src + (size_t)e * DIM * DIM);
        float4 u1 = *(const float4*)(src + (size_t)e * DIM * DIM + 4);
        s0 += u0.x; s1 += u0.y; s2 += u0.z; s3 += u0.w;
        s4 += u1.x; s5 += u1.y; s6 += u1.z; s7 += u1.w;
    }
    uint4 v;
    v.x = pk2bf(s0, s1); v.y = pk2bf(s2, s3);
    v.z = pk2bf(s4, s5); v.w = pk2bf(s6, s7);

    const int F  = f >> 6, j = (f >> 4) & 3, lr = f & 15;
    const int sl = q >> 2, lg = q & 3;
    const int idx16 = ((F * 4 + j) * 16 + sl) * 64 + (lg * 16 + lr);
    *(uint4*)(Bfrag + (size_t)idx16 * 8) = v;

    if (g < DIM / 4) {
        float4 bs = make_float4(0.f, 0.f, 0.f, 0.f);
#pragma unroll
        for (int e = 0; e < NEXP; ++e) {
            float4 u = *(const float4*)(b + e * DIM + g * 4);
            bs.x += u.x; bs.y += u.y; bs.z += u.z; bs.w += u.w;
        }
        *(float4*)(bsum + g * 4) = bs;
    }
}

// ---------------- main GEMM: 2-tile pipelined, dense-B, stage-A-LDS ----------------
// Block = 2 tiles of [64 tokens x all 512 features]; 8 waves, wave w owns features
// [w*64,(w+1)*64). Grid 256 = 1 block/CU.
__global__ __launch_bounds__(512, 2) void moe_gemm(const float* __restrict__ x,
                                                   const float* __restrict__ wts,
                                                   const unsigned short* __restrict__ Bf,
                                                   const float* __restrict__ bsum,
                                                   float* __restrict__ out) {
    __shared__ __align__(16) unsigned char ldsA[BM * DIM * 2];   // 64 KB, single buffer

    const int tid  = threadIdx.x;
    const int lane = tid & 63;
    const int w    = tid >> 6;       // wave 0..7
    const int lr   = lane & 15;
    const int lg   = lane >> 4;
    const int blk  = blockIdx.x;
    const int f0   = w * 64;

    // ---- A staging: thread -> row tid>>3 (0..63), granule slot as0 = tid&7.
    //      Granules g = as0 + u*8 (u=0..7), each 8 f32 -> 16B bf16, XOR-swizzled.
    const int arow = tid >> 3;
    const int as0  = tid & 7;
    unsigned char* arowp = ldsA + arow * 1024;

    float4 r[16];    // staging registers, held across the previous tile's K-loop
    auto loadQ = [&](int tile) {
        const float* src = x + (size_t)((blk * TILES + tile) * BM + arow) * DIM;
#pragma unroll
        for (int u = 0; u < 8; ++u) {
            const float* p = src + (as0 + u * 8) * 8;
            r[2 * u]     = *(const float4*)p;
            r[2 * u + 1] = *(const float4*)(p + 4);
        }
    };
    auto stageWrite = [&]() {
#pragma unroll
        for (int u = 0; u < 8; ++u) {
            const int g  = as0 + u * 8;
            const int sg = (g & ~7) | ((g ^ arow) & 7);   // XOR swizzle (proven)
            uint4 v;
            v.x = pk2bf(r[2 * u].x,     r[2 * u].y);
            v.y = pk2bf(r[2 * u].z,     r[2 * u].w);
            v.z = pk2bf(r[2 * u + 1].x, r[2 * u + 1].y);
            v.w = pk2bf(r[2 * u + 1].z, r[2 * u + 1].w);
            *(uint4*)(arowp + sg * 16) = v;
        }
    };

    // ---- dense B stream base (R6-proven): wave w's fragment block, lane's 16B slot
    const bf16x8* bfr = (const bf16x8*)Bf + (size_t)w * 4096 + lane;   // + j*1024 + s*64

    f32x4 acc[4][4];
    bf16x8 bE[4], bO[4], af[4];

    auto loadB = [&](int s, bf16x8 (&bb)[4]) {
#pragma unroll
        for (int j = 0; j < 4; ++j)
            bb[j] = bfr[j * 1024 + s * 64];
    };
    auto sliceA = [&](int s) {
#pragma unroll
        for (int i = 0; i < 4; ++i) {
            const int row = i * 16 + lr;
            const int gsl = s * 4 + lg;
            const int sw  = (gsl & ~7) | ((gsl ^ row) & 7);
            af[i] = *(const bf16x8*)(ldsA + row * 1024 + sw * 16);
        }
    };
    auto mf = [&](bf16x8 (&bb)[4]) {
#pragma unroll
        for (int j = 0; j < 4; ++j)
#pragma unroll
            for (int i = 0; i < 4; ++i)
                acc[j][i] = __builtin_amdgcn_mfma_f32_16x16x32_bf16(bb[j], af[i], acc[j][i], 0, 0, 0);
    };
    auto kloop = [&]() {
#pragma unroll
        for (int j = 0; j < 4; ++j)
#pragma unroll
            for (int i = 0; i < 4; ++i)
                acc[j][i] = f32x4{0.f, 0.f, 0.f, 0.f};
        loadB(0, bE);
#pragma unroll
        for (int it = 0; it < 8; ++it) {
            loadB(2 * it + 1, bO);                      // prefetch odd slice
            sliceA(2 * it);
            mf(bE);
            if (it < 7) loadB(2 * it + 2, bE);          // prefetch even slice
            sliceA(2 * it + 1);
            mf(bO);
        }
    };
    auto epilogue = [&](int tile) {
        const int m0 = (blk * TILES + tile) * BM;
        f32x4 bs4[4];
#pragma unroll
        for (int j = 0; j < 4; ++j)
            bs4[j] = *(const f32x4*)(bsum + f0 + j * 16 + lg * 4);
#pragma unroll
        for (int i = 0; i < 4; ++i) {
            const int row = m0 + i * 16 + lr;
            const float wt = wts[row];
#pragma unroll
            for (int j = 0; j < 4; ++j) {
                f32x4 v;
                v[0] = wt * (acc[j][i][0] + bs4[j][0]);
                v[1] = wt * (acc[j][i][1] + bs4[j][1]);
                v[2] = wt * (acc[j][i][2] + bs4[j][2]);
                v[3] = wt * (acc[j][i][3] + bs4[j][3]);
                *(f32x4*)(out + (size_t)row * DIM + f0 + j * 16 + lg * 4) = v;
            }
        }
    };

    // ================= pipeline =================
    // tile 0: stage
    loadQ(0);
    stageWrite();
    __syncthreads();

    // tile 1 A-loads issued EARLY, pinned before tile 0's K-loop
    loadQ(1);
    __builtin_amdgcn_sched_barrier(0);

    kloop();           // tile 0 compute (B from L2, A from LDS) -- covers tile1 reads
    epilogue(0);       // stores issue, drain under what follows

    __syncthreads();   // all waves done reading ldsA (tile 0)
    stageWrite();      // tile 1 -> LDS (dependency-waits the early loads)
    __syncthreads();   // tile 1 visible

    kloop();           // tile 1 compute
    epilogue(1);
}

extern "C" void kernel_launch(void* const* d_in, const int* in_sizes, int n_in,
                              void* d_out, int out_size, void* d_ws, size_t ws_size,
                              hipStream_t stream) {
    const float* x   = (const float*)d_in[0];   // [N, D]
    const float* wts = (const float*)d_in[1];   // [N, 1]
    const float* W   = (const float*)d_in[2];   // [E, D, D]
    const float* b   = (const float*)d_in[3];   // [E, D]
    float* out       = (float*)d_out;           // [N, D]

    unsigned short* Bfrag = (unsigned short*)d_ws;                    // 512 KB bf16
    float*          bsum  = (float*)((char*)d_ws + DIM * DIM * 2);    // 2 KB f32

    moe_prep<<<dim3((DIM * DIM / 8) / 256), dim3(256), 0, stream>>>(W, b, Bfrag, bsum);

    moe_gemm<<<dim3(N_TOK / (BM * TILES)), dim3(512), 0, stream>>>(x, wts, Bfrag, bsum, out);
}